// Round 2
// baseline (696.868 us; speedup 1.0000x reference)
//
#include <hip/hip_runtime.h>
#include <math.h>

#define CH 64
#define TQ 1024
#define TKV 4096
#define ATT 32   // t rows per block
#define ASB 64   // s (kv) tile

// ---------------- 32x32 2D DFT + fftshift ----------------
// One block per transform. Computes Y = F X F^T (complex), stores shifted,
// scaled, as separate re/im planes.
__global__ __launch_bounds__(256) void fft2_shift(
    const float* __restrict__ src, float* __restrict__ dre, float* __restrict__ dimg,
    int rows_per_b, int c_base, int row_stride, int rcount, float scale)
{
  __shared__ float X[1024];
  __shared__ float2 T1[1024];
  __shared__ float2 tw[32];
  const int i = blockIdx.x;
  const int r = i % rcount;
  const int c = (i / rcount) & 63;
  const int b = i / (rcount * 64);
  const int src_off = (b * rows_per_b + c_base + c) * row_stride + r * 1024;
  const int dst_off = ((b * 64 + c) * rcount + r) * 1024;
  const int tid = threadIdx.x;
  #pragma unroll
  for (int j = 0; j < 4; j++) X[tid + j * 256] = src[src_off + tid + j * 256];
  if (tid < 32) {
    float sn, cs;
    sincosf(-6.283185307179586f * (float)tid / 32.0f, &sn, &cs);
    tw[tid] = make_float2(cs, sn);
  }
  __syncthreads();
  // stage 1: T1[u1][n2] = sum_n1 X[n1][n2] * w(u1*n1)
  #pragma unroll
  for (int j = 0; j < 4; j++) {
    int idx = tid + j * 256;
    int u1 = idx >> 5, n2 = idx & 31;
    float re = 0.f, im = 0.f;
    #pragma unroll
    for (int n1 = 0; n1 < 32; n1++) {
      float x = X[n1 * 32 + n2];
      float2 w = tw[(u1 * n1) & 31];
      re += x * w.x;
      im += x * w.y;
    }
    T1[idx] = make_float2(re, im);
  }
  __syncthreads();
  // stage 2: Y[u1][u2] = sum_n2 T1[u1][n2] * w(u2*n2), store fftshifted
  #pragma unroll
  for (int j = 0; j < 4; j++) {
    int idx = tid + j * 256;
    int u1 = idx >> 5, u2 = idx & 31;
    float re = 0.f, im = 0.f;
    #pragma unroll
    for (int n2 = 0; n2 < 32; n2++) {
      float2 a = T1[u1 * 32 + n2];
      float2 w = tw[(u2 * n2) & 31];
      re += a.x * w.x - a.y * w.y;
      im += a.x * w.y + a.y * w.x;
    }
    int su1 = (u1 + 16) & 31, su2 = (u2 + 16) & 31;
    dre[dst_off + su1 * 32 + su2] = re * scale;
    dimg[dst_off + su1 * 32 + su2] = im * scale;
  }
}

// ---------------- fused complex-score flash attention ----------------
// grid = 8 b * 32 t-blocks (b = blockIdx&7 for XCD/L2 affinity), 512 threads.
// S phase mapping:  cg2 = tid&1 (c half), sg = (tid>>1)&15 (4 s each),
//                   tg = tid>>5 (2 t each).
// acc phase mapping: ta = tid&15 (2 t), ca = (tid>>4)&15 (c = ca+16k),
//                    sg2 = tid>>8 (s half of tile; reduced at the end).
__global__ __launch_bounds__(512) void attn_fused(
    const float* __restrict__ QfRe, const float* __restrict__ QfIm,
    const float* __restrict__ KfRe, const float* __restrict__ KfIm,
    const float* __restrict__ VfRe, const float* __restrict__ VfIm,
    float* __restrict__ out)
{
  __shared__ __align__(16) float2 qT[CH][ATT + 2];     // [c][t]
  __shared__ __align__(16) float  kreS[CH][ASB + 4];   // [c][s]
  __shared__ __align__(16) float  kimS[CH][ASB + 4];
  __shared__ __align__(16) float2 vS[ASB][CH + 2];     // [s][c]
  __shared__ __align__(16) float2 p2[ASB][ATT + 3];    // [s][t] (p_re, p_im)
  __shared__ float2 alpha2[ATT];
  __shared__ float2 l2[ATT];

  const int tid = threadIdx.x;
  const int b = blockIdx.x & 7;
  const int t0 = (blockIdx.x >> 3) * ATT;

  // stage Q tile once
  #pragma unroll
  for (int j = 0; j < 4; j++) {
    int i = tid + j * 512;
    int c = i >> 5, tl = i & 31;
    int g = (b * CH + c) * TQ + t0 + tl;
    qT[c][tl] = make_float2(QfRe[g], QfIm[g]);
  }

  const int cg2 = tid & 1;
  const int sg = (tid >> 1) & 15;
  const int tg = tid >> 5;
  const int ta = tid & 15;
  const int ca = (tid >> 4) & 15;
  const int sg2 = tid >> 8;

  float m_re[2] = {-1e30f, -1e30f}, m_im[2] = {-1e30f, -1e30f};
  float l_re[2] = {0.f, 0.f}, l_im[2] = {0.f, 0.f};
  float are[2][4] = {{0.f, 0.f, 0.f, 0.f}, {0.f, 0.f, 0.f, 0.f}};
  float aim[2][4] = {{0.f, 0.f, 0.f, 0.f}, {0.f, 0.f, 0.f, 0.f}};

  for (int s0 = 0; s0 < TKV; s0 += ASB) {
    __syncthreads();   // previous tile fully consumed before restaging
    // stage K/V tile
    #pragma unroll
    for (int j = 0; j < 8; j++) {
      int i = tid + j * 512;
      int c = i >> 6, sl = i & 63;
      int g = (b * CH + c) * TKV + s0 + sl;
      kreS[c][sl] = KfRe[g];
      kimS[c][sl] = KfIm[g];
      vS[sl][c] = make_float2(VfRe[g], VfIm[g]);
    }
    __syncthreads();

    // ---- S = Qf^T Kf over this thread's half of c ----
    float sr[2][4], si[2][4];
    #pragma unroll
    for (int tt = 0; tt < 2; tt++)
      #pragma unroll
      for (int jj = 0; jj < 4; jj++) { sr[tt][jj] = 0.f; si[tt][jj] = 0.f; }
    {
      const int cbase = cg2 * 32;
      #pragma unroll 8
      for (int c = 0; c < 32; c++) {
        const int cc = cbase + c;
        const float4 qq = *(const float4*)&qT[cc][2 * tg];
        const float4 kr4 = *(const float4*)&kreS[cc][4 * sg];
        const float4 ki4 = *(const float4*)&kimS[cc][4 * sg];
        const float qrA[2] = {qq.x, qq.z};
        const float qiA[2] = {qq.y, qq.w};
        const float krA[4] = {kr4.x, kr4.y, kr4.z, kr4.w};
        const float kiA[4] = {ki4.x, ki4.y, ki4.z, ki4.w};
        #pragma unroll
        for (int tt = 0; tt < 2; tt++)
          #pragma unroll
          for (int jj = 0; jj < 4; jj++) {
            sr[tt][jj] += qrA[tt] * krA[jj] - qiA[tt] * kiA[jj];
            si[tt][jj] += qrA[tt] * kiA[jj] + qiA[tt] * krA[jj];
          }
      }
    }
    // reduce the two c-halves (lanes differ in bit 0)
    #pragma unroll
    for (int tt = 0; tt < 2; tt++)
      #pragma unroll
      for (int jj = 0; jj < 4; jj++) {
        sr[tt][jj] += __shfl_xor(sr[tt][jj], 1);
        si[tt][jj] += __shfl_xor(si[tt][jj], 1);
      }

    // ---- online softmax (re & im independently) ----
    #pragma unroll
    for (int tt = 0; tt < 2; tt++) {
      float mt_r = fmaxf(fmaxf(sr[tt][0], sr[tt][1]), fmaxf(sr[tt][2], sr[tt][3]));
      float mt_i = fmaxf(fmaxf(si[tt][0], si[tt][1]), fmaxf(si[tt][2], si[tt][3]));
      #pragma unroll
      for (int msk = 2; msk <= 16; msk <<= 1) {
        mt_r = fmaxf(mt_r, __shfl_xor(mt_r, msk));
        mt_i = fmaxf(mt_i, __shfl_xor(mt_i, msk));
      }
      const float mn_r = fmaxf(m_re[tt], mt_r);
      const float mn_i = fmaxf(m_im[tt], mt_i);
      const float al_r = __expf(m_re[tt] - mn_r);
      const float al_i = __expf(m_im[tt] - mn_i);
      float pr[4], pi[4];
      float sum_r = 0.f, sum_i = 0.f;
      #pragma unroll
      for (int jj = 0; jj < 4; jj++) {
        pr[jj] = __expf(sr[tt][jj] - mn_r);
        pi[jj] = __expf(si[tt][jj] - mn_i);
        sum_r += pr[jj];
        sum_i += pi[jj];
      }
      #pragma unroll
      for (int msk = 2; msk <= 16; msk <<= 1) {
        sum_r += __shfl_xor(sum_r, msk);
        sum_i += __shfl_xor(sum_i, msk);
      }
      l_re[tt] = l_re[tt] * al_r + sum_r;
      l_im[tt] = l_im[tt] * al_i + sum_i;
      m_re[tt] = mn_r;
      m_im[tt] = mn_i;
      if (cg2 == 0) {
        #pragma unroll
        for (int jj = 0; jj < 4; jj++)
          p2[4 * sg + jj][2 * tg + tt] = make_float2(pr[jj], pi[jj]);
        if (sg == 0) alpha2[2 * tg + tt] = make_float2(al_r, al_i);
      }
    }
    __syncthreads();

    // ---- accumulate a += P_re*V_re + P_im*V_im over this tile ----
    {
      const float2 a0 = alpha2[2 * ta];
      const float2 a1 = alpha2[2 * ta + 1];
      #pragma unroll
      for (int cc = 0; cc < 4; cc++) {
        are[0][cc] *= a0.x; aim[0][cc] *= a0.y;
        are[1][cc] *= a1.x; aim[1][cc] *= a1.y;
      }
      const int sbase = sg2 * 32;
      #pragma unroll 4
      for (int s = 0; s < 32; s++) {
        const int ss = sbase + s;
        const float2 pa = p2[ss][2 * ta];
        const float2 pb = p2[ss][2 * ta + 1];
        const float2 v0 = vS[ss][ca];
        const float2 v1 = vS[ss][ca + 16];
        const float2 v2 = vS[ss][ca + 32];
        const float2 v3 = vS[ss][ca + 48];
        are[0][0] += pa.x * v0.x; aim[0][0] += pa.y * v0.y;
        are[0][1] += pa.x * v1.x; aim[0][1] += pa.y * v1.y;
        are[0][2] += pa.x * v2.x; aim[0][2] += pa.y * v2.y;
        are[0][3] += pa.x * v3.x; aim[0][3] += pa.y * v3.y;
        are[1][0] += pb.x * v0.x; aim[1][0] += pb.y * v0.y;
        are[1][1] += pb.x * v1.x; aim[1][1] += pb.y * v1.y;
        are[1][2] += pb.x * v2.x; aim[1][2] += pb.y * v2.y;
        are[1][3] += pb.x * v3.x; aim[1][3] += pb.y * v3.y;
      }
    }
  }

  // publish final softmax denominators
  if (cg2 == 0 && sg == 0) {
    l2[2 * tg] = make_float2(l_re[0], l_im[0]);
    l2[2 * tg + 1] = make_float2(l_re[1], l_im[1]);
  }
  __syncthreads();

  // reduce the two sg2 s-halves through LDS scratch (reuse kreS/kimS)
  float* scrR = &kreS[0][0];
  float* scrI = &kimS[0][0];
  if (sg2 == 1) {
    const int base = (tid & 255) * 8;
    #pragma unroll
    for (int tt = 0; tt < 2; tt++)
      #pragma unroll
      for (int cc = 0; cc < 4; cc++) {
        scrR[base + tt * 4 + cc] = are[tt][cc];
        scrI[base + tt * 4 + cc] = aim[tt][cc];
      }
  }
  __syncthreads();
  if (sg2 == 0) {
    const int base = tid * 8;
    const float2 lt0 = l2[2 * ta];
    const float2 lt1 = l2[2 * ta + 1];
    #pragma unroll
    for (int cc = 0; cc < 4; cc++) {
      const float r0 = are[0][cc] + scrR[base + cc];
      const float i0 = aim[0][cc] + scrI[base + cc];
      const float r1 = are[1][cc] + scrR[base + 4 + cc];
      const float i1 = aim[1][cc] + scrI[base + 4 + cc];
      const float o0 = r0 / lt0.x + i0 / lt0.y;
      const float o1 = r1 / lt1.x + i1 / lt1.y;
      const int c = ca + 16 * cc;
      const int g = (b * CH + c) * TQ + t0 + 2 * ta;
      *(float2*)&out[g] = make_float2(o0, o1);
    }
  }
}

extern "C" void kernel_launch(void* const* d_in, const int* in_sizes, int n_in,
                              void* d_out, int out_size, void* d_ws, size_t ws_size,
                              hipStream_t stream) {
  const float* q  = (const float*)d_in[0];
  const float* kv = (const float*)d_in[1];
  float* ws = (float*)d_ws;
  // workspace layout (floats): Qf re/im [8*64*1024], Kf re/im [8*64*4096],
  // Vf re/im [8*64*4096]  -> total 9,437,184 floats = 36 MiB
  float* QfRe = ws;
  float* QfIm = QfRe + 524288;
  float* KfRe = QfIm + 524288;
  float* KfIm = KfRe + 2097152;
  float* VfRe = KfIm + 2097152;
  float* VfIm = VfRe + 2097152;
  float* out = (float*)d_out;

  const float sc = 0.35355339059327373f;   // 1/ch^(1/4), folded into Qf and Kf
  // q: [8 b][64 c][1024], one 32x32 block each
  fft2_shift<<<512, 256, 0, stream>>>(q, QfRe, QfIm, 64, 0, 1024, 1, sc);
  // k: kv rows 0..63 per b, 4 ratio blocks
  fft2_shift<<<2048, 256, 0, stream>>>(kv, KfRe, KfIm, 128, 0, 4096, 4, sc);
  // v: kv rows 64..127 per b; fold 1/1024 (ifft norm) into Vf
  fft2_shift<<<2048, 256, 0, stream>>>(kv, VfRe, VfIm, 128, 64, 4096, 4, 1.0f / 1024.0f);

  attn_fused<<<256, 512, 0, stream>>>(QfRe, QfIm, KfRe, KfIm, VfRe, VfIm, out);
}

// Round 6
// 201.925 us; speedup vs baseline: 3.4511x; 3.4511x over previous
//
#include <hip/hip_runtime.h>
#include <math.h>

typedef _Float16 half8 __attribute__((ext_vector_type(8)));
typedef float f32x16 __attribute__((ext_vector_type(16)));

#define L2E 1.4426950408889634f
#define KPLANE (8*4096*64)
#define QPLANE (8*1024*64)
#define VPLANE (8*64*4096)

// ---------------- 32x32 2D DFT + fftshift -> fp16 planes ----------------
// MODE 0: Q -> [b][t][c] H/L re/im (d0..d3), scale = sc*log2(e)
// MODE 1: K -> [b][s][c] H/L re/im (d0..d3), scale = sc
// MODE 2: V -> [b][c][s] re/im fp16 (d0,d1), scale = 1/1024
template<int MODE>
__global__ __launch_bounds__(256) void fft2_prep(
    const float* __restrict__ src,
    _Float16* __restrict__ d0, _Float16* __restrict__ d1,
    _Float16* __restrict__ d2, _Float16* __restrict__ d3,
    int rows_per_b, int c_base, int row_stride, int rcount, float scale)
{
  __shared__ float X[1024];
  __shared__ float2 T1[1024];
  __shared__ float2 tw[32];
  const int i = blockIdx.x;
  const int r = i % rcount;
  const int c = (i / rcount) & 63;
  const int b = i / (rcount * 64);
  const int src_off = (b * rows_per_b + c_base + c) * row_stride + r * 1024;
  const int tid = threadIdx.x;
  #pragma unroll
  for (int j = 0; j < 4; j++) X[tid + j * 256] = src[src_off + tid + j * 256];
  if (tid < 32) {
    float sn, cs;
    sincosf(-6.283185307179586f * (float)tid / 32.0f, &sn, &cs);
    tw[tid] = make_float2(cs, sn);
  }
  __syncthreads();
  #pragma unroll
  for (int j = 0; j < 4; j++) {
    int idx = tid + j * 256;
    int u1 = idx >> 5, n2 = idx & 31;
    float re = 0.f, im = 0.f;
    #pragma unroll
    for (int n1 = 0; n1 < 32; n1++) {
      float x = X[n1 * 32 + n2];
      float2 w = tw[(u1 * n1) & 31];
      re += x * w.x;
      im += x * w.y;
    }
    T1[idx] = make_float2(re, im);
  }
  __syncthreads();
  #pragma unroll
  for (int j = 0; j < 4; j++) {
    int idx = tid + j * 256;
    int u1 = idx >> 5, u2 = idx & 31;
    float re = 0.f, im = 0.f;
    #pragma unroll
    for (int n2 = 0; n2 < 32; n2++) {
      float2 a = T1[u1 * 32 + n2];
      float2 w = tw[(u2 * n2) & 31];
      re += a.x * w.x - a.y * w.y;
      im += a.x * w.y + a.y * w.x;
    }
    int su1 = (u1 + 16) & 31, su2 = (u2 + 16) & 31;
    int pos = su1 * 32 + su2;
    float R = re * scale, I = im * scale;
    if (MODE == 0) {
      int o = (b * 1024 + pos) * 64 + c;
      _Float16 rh = (_Float16)R; _Float16 ih = (_Float16)I;
      d0[o] = rh; d1[o] = (_Float16)(R - (float)rh);
      d2[o] = ih; d3[o] = (_Float16)(I - (float)ih);
    } else if (MODE == 1) {
      int s = r * 1024 + pos;
      int o = (b * 4096 + s) * 64 + c;
      _Float16 rh = (_Float16)R; _Float16 ih = (_Float16)I;
      d0[o] = rh; d1[o] = (_Float16)(R - (float)rh);
      d2[o] = ih; d3[o] = (_Float16)(I - (float)ih);
    } else {
      int s = r * 1024 + pos;
      int o = (b * 64 + c) * 4096 + s;
      d0[o] = (_Float16)R; d1[o] = (_Float16)I;
    }
  }
}

// write this lane's 16 P values (fp16 pairs) into pb[idx] (u32 = (s2i, s2i+1)),
// idx = s/2 in {0,1,4,5,8,9,12,13} + 2*lh  (C-layout rows (rr&3)+8*(rr>>2)+4lh)
static __device__ inline void storeP(unsigned* pb, const float* p, int lh) {
  #pragma unroll
  for (int u = 0; u < 8; u++) {
    int base = ((u & 1) * 2) + ((u >> 1) * 8) + 4 * lh;  // 0,2,8,10,16,18,24,26 (+4lh)
    unsigned short h0 = __builtin_bit_cast(unsigned short, (_Float16)p[2 * u]);
    unsigned short h1 = __builtin_bit_cast(unsigned short, (_Float16)p[2 * u + 1]);
    pb[base >> 1] = (unsigned)h0 | ((unsigned)h1 << 16);
  }
}
static __device__ inline half8 loadP(const unsigned* rp) {
  union { uint4 u; half8 h; } U;
  U.u = *(const uint4*)rp;
  return U.h;
}

// ---------------- MFMA flash attention over complex scores ----------------
// grid 256 = 8 b x 32 t-tiles; 512 threads = 8 warps, warp w owns s-chunk
// [w*512, w*512+512). Scores: C = mfma(A=K[s,c], B=Q[t,c]) -> lane col=t,
// reg rows=s. Split-fp16 3-product for fp32-grade S. PV: O^T = mfma(A=V[c,s],
// B=P[t,s]) -> lane col=t (rescale lane-uniform), reg rows=c.
// P repack routed through per-warp LDS (assumption-free; no permlane).
__global__ __launch_bounds__(512, 1) void attn_mfma(
    const _Float16* __restrict__ KrH, const _Float16* __restrict__ KrL,
    const _Float16* __restrict__ KiH, const _Float16* __restrict__ KiL,
    const _Float16* __restrict__ QrH, const _Float16* __restrict__ QrL,
    const _Float16* __restrict__ QiH, const _Float16* __restrict__ QiL,
    const _Float16* __restrict__ Vre, const _Float16* __restrict__ Vim,
    float* __restrict__ out)
{
  __shared__ __align__(16) _Float16 qlds[4][4][64][8];  // [plane][kstep][lane][8]
  __shared__ __align__(16) unsigned pbufR[8][32][20];   // [warp][t][s-pair], pad 20
  __shared__ __align__(16) unsigned pbufI[8][32][20];
  __shared__ float mlb[8][32][5];
  __shared__ float obuf[8][32][33];

  const int tid = threadIdx.x;
  const int lane = tid & 63;
  const int warp = tid >> 6;
  const int b = blockIdx.x & 7;
  const int t0 = (blockIdx.x >> 3) << 5;
  const int lm = lane & 31, lh = lane >> 5;

  // stage Q fragments (frag-major, conflict-free reads later)
  {
    const _Float16* qp[4] = {QrH, QrL, QiH, QiL};
    #pragma unroll
    for (int jj = 0; jj < 2; jj++) {
      int idx = tid + jj * 512;
      int pl = idx >> 8, ks = (idx >> 6) & 3, ln = idx & 63;
      int t = ln & 31, hh = ln >> 5;
      const _Float16* s = qp[pl] + ((b * 1024 + t0 + t) * 64 + ks * 16 + hh * 8);
      *(half8*)&qlds[pl][ks][ln][0] = *(const half8*)s;
    }
  }
  __syncthreads();

  int kbase = (b * 4096 + warp * 512 + lm) * 64 + lh * 8;
  const int vbase0 = (b * 64 + lm) * 4096 + warp * 512 + lh * 8;
  const int vbase1 = vbase0 + 32 * 4096;

  float m_r = -3e38f, m_i = -3e38f, l_r = 0.f, l_i = 0.f;
  f32x16 Or0 = (f32x16)(0.0f), Or1 = (f32x16)(0.0f);
  f32x16 Oi0 = (f32x16)(0.0f), Oi1 = (f32x16)(0.0f);

  #pragma unroll 1
  for (int it = 0; it < 16; ++it) {
    f32x16 A1 = (f32x16)(0.0f), A2 = (f32x16)(0.0f), SI = (f32x16)(0.0f);
    #pragma unroll
    for (int ks = 0; ks < 4; ks++) {
      half8 qrh = *(const half8*)&qlds[0][ks][lane][0];
      half8 qrl = *(const half8*)&qlds[1][ks][lane][0];
      half8 qih = *(const half8*)&qlds[2][ks][lane][0];
      half8 qil = *(const half8*)&qlds[3][ks][lane][0];
      const int ko = kbase + ks * 16;
      half8 krh = *(const half8*)(KrH + ko);
      half8 krl = *(const half8*)(KrL + ko);
      half8 kih = *(const half8*)(KiH + ko);
      half8 kil = *(const half8*)(KiL + ko);
      // S_re = Qr*Kr - Qi*Ki  (A1 - A2);  S_im = Qr*Ki + Qi*Kr  (SI)
      A1 = __builtin_amdgcn_mfma_f32_32x32x16_f16(krh, qrh, A1, 0, 0, 0);
      A2 = __builtin_amdgcn_mfma_f32_32x32x16_f16(kih, qih, A2, 0, 0, 0);
      SI = __builtin_amdgcn_mfma_f32_32x32x16_f16(kih, qrh, SI, 0, 0, 0);
      A1 = __builtin_amdgcn_mfma_f32_32x32x16_f16(krh, qrl, A1, 0, 0, 0);
      A2 = __builtin_amdgcn_mfma_f32_32x32x16_f16(kih, qil, A2, 0, 0, 0);
      SI = __builtin_amdgcn_mfma_f32_32x32x16_f16(krh, qih, SI, 0, 0, 0);
      A1 = __builtin_amdgcn_mfma_f32_32x32x16_f16(krl, qrh, A1, 0, 0, 0);
      A2 = __builtin_amdgcn_mfma_f32_32x32x16_f16(kil, qih, A2, 0, 0, 0);
      SI = __builtin_amdgcn_mfma_f32_32x32x16_f16(kil, qrh, SI, 0, 0, 0);
      SI = __builtin_amdgcn_mfma_f32_32x32x16_f16(kih, qrl, SI, 0, 0, 0);
      SI = __builtin_amdgcn_mfma_f32_32x32x16_f16(krl, qih, SI, 0, 0, 0);
      SI = __builtin_amdgcn_mfma_f32_32x32x16_f16(krh, qil, SI, 0, 0, 0);
    }

    float sre[16], sim[16];
    #pragma unroll
    for (int rr = 0; rr < 16; rr++) { sre[rr] = A1[rr] - A2[rr]; sim[rr] = SI[rr]; }

    float mtr = sre[0], mti = sim[0];
    #pragma unroll
    for (int rr = 1; rr < 16; rr++) { mtr = fmaxf(mtr, sre[rr]); mti = fmaxf(mti, sim[rr]); }
    mtr = fmaxf(mtr, __shfl_xor(mtr, 32));
    mti = fmaxf(mti, __shfl_xor(mti, 32));

    // ---- re softmax (log2 units; defer-max threshold 11.5 bits ~ 8 nats) ----
    float pr[16], pi[16];
    {
      float mn = fmaxf(m_r, mtr);
      if (__ballot(mtr > m_r + 11.5f)) {
        float al = exp2f(m_r - mn);
        l_r *= al; m_r = mn;
        #pragma unroll
        for (int rr = 0; rr < 16; rr++) { Or0[rr] *= al; Or1[rr] *= al; }
      }
      float sm = 0.f;
      #pragma unroll
      for (int rr = 0; rr < 16; rr++) { pr[rr] = exp2f(sre[rr] - m_r); sm += pr[rr]; }
      l_r += sm + __shfl_xor(sm, 32);
    }
    // ---- im softmax ----
    {
      float mn = fmaxf(m_i, mti);
      if (__ballot(mti > m_i + 11.5f)) {
        float al = exp2f(m_i - mn);
        l_i *= al; m_i = mn;
        #pragma unroll
        for (int rr = 0; rr < 16; rr++) { Oi0[rr] *= al; Oi1[rr] *= al; }
      }
      float sm = 0.f;
      #pragma unroll
      for (int rr = 0; rr < 16; rr++) { pi[rr] = exp2f(sim[rr] - m_i); sm += pi[rr]; }
      l_i += sm + __shfl_xor(sm, 32);
    }

    // ---- repack P via per-warp LDS (same-wave write->read, no barrier) ----
    storeP(&pbufR[warp][lm][0], pr, lh);
    storeP(&pbufI[warp][lm][0], pi, lh);

    // ---- PV: O^T += V * P ----
    #pragma unroll
    for (int h = 0; h < 2; h++) {
      half8 pfr = loadP(&pbufR[warp][lm][h * 8 + 4 * lh]);
      half8 pfi = loadP(&pbufI[warp][lm][h * 8 + 4 * lh]);
      const int vo = it * 32 + h * 16;
      half8 v0r = *(const half8*)(Vre + vbase0 + vo);
      half8 v0i = *(const half8*)(Vim + vbase0 + vo);
      half8 v1r = *(const half8*)(Vre + vbase1 + vo);
      half8 v1i = *(const half8*)(Vim + vbase1 + vo);
      Or0 = __builtin_amdgcn_mfma_f32_32x32x16_f16(v0r, pfr, Or0, 0, 0, 0);
      Oi0 = __builtin_amdgcn_mfma_f32_32x32x16_f16(v0i, pfi, Oi0, 0, 0, 0);
      Or1 = __builtin_amdgcn_mfma_f32_32x32x16_f16(v1r, pfr, Or1, 0, 0, 0);
      Oi1 = __builtin_amdgcn_mfma_f32_32x32x16_f16(v1i, pfi, Oi1, 0, 0, 0);
    }
    kbase += 32 * 64;
  }

  // ---- merge the 8 warps' partial softmax states ----
  if (lane < 32) {
    mlb[warp][lane][0] = m_r; mlb[warp][lane][1] = l_r;
    mlb[warp][lane][2] = m_i; mlb[warp][lane][3] = l_i;
  }
  __syncthreads();
  float Mr = -3e38f, Mi = -3e38f;
  #pragma unroll
  for (int w = 0; w < 8; w++) {
    Mr = fmaxf(Mr, mlb[w][lm][0]);
    Mi = fmaxf(Mi, mlb[w][lm][2]);
  }
  float Lr = 0.f, Li = 0.f;
  #pragma unroll
  for (int w = 0; w < 8; w++) {
    Lr += mlb[w][lm][1] * exp2f(mlb[w][lm][0] - Mr);
    Li += mlb[w][lm][3] * exp2f(mlb[w][lm][2] - Mi);
  }
  const float fr = exp2f(m_r - Mr) / Lr;
  const float fi = exp2f(m_i - Mi) / Li;

  // ct = 0 (c 0..31)
  #pragma unroll
  for (int rr = 0; rr < 16; rr++) {
    int cl = (rr & 3) + 8 * (rr >> 2) + 4 * lh;
    obuf[warp][cl][lm] = Or0[rr] * fr + Oi0[rr] * fi;
  }
  __syncthreads();
  {
    int c = tid >> 4, t2 = (tid & 15) * 2;
    float2 acc = make_float2(0.f, 0.f);
    #pragma unroll
    for (int w = 0; w < 8; w++) { acc.x += obuf[w][c][t2]; acc.y += obuf[w][c][t2 + 1]; }
    *(float2*)&out[(b * 64 + c) * 1024 + t0 + t2] = acc;
  }
  __syncthreads();
  // ct = 1 (c 32..63)
  #pragma unroll
  for (int rr = 0; rr < 16; rr++) {
    int cl = (rr & 3) + 8 * (rr >> 2) + 4 * lh;
    obuf[warp][cl][lm] = Or1[rr] * fr + Oi1[rr] * fi;
  }
  __syncthreads();
  {
    int c = tid >> 4, t2 = (tid & 15) * 2;
    float2 acc = make_float2(0.f, 0.f);
    #pragma unroll
    for (int w = 0; w < 8; w++) { acc.x += obuf[w][c][t2]; acc.y += obuf[w][c][t2 + 1]; }
    *(float2*)&out[(b * 64 + 32 + c) * 1024 + t0 + t2] = acc;
  }
}

extern "C" void kernel_launch(void* const* d_in, const int* in_sizes, int n_in,
                              void* d_out, int out_size, void* d_ws, size_t ws_size,
                              hipStream_t stream) {
  const float* q  = (const float*)d_in[0];
  const float* kv = (const float*)d_in[1];
  _Float16* base = (_Float16*)d_ws;
  // halves: K 4 planes of 2M, Q 4 planes of 0.5M, V 2 planes of 2M -> 28 MB
  _Float16* KrH = base;
  _Float16* KrL = KrH + KPLANE;
  _Float16* KiH = KrL + KPLANE;
  _Float16* KiL = KiH + KPLANE;
  _Float16* QrH = KiL + KPLANE;
  _Float16* QrL = QrH + QPLANE;
  _Float16* QiH = QrL + QPLANE;
  _Float16* QiL = QiH + QPLANE;
  _Float16* Vre = QiL + QPLANE;
  _Float16* Vim = Vre + VPLANE;
  float* out = (float*)d_out;

  const float sc = 0.35355339059327373f;  // ch^(-1/4)
  fft2_prep<0><<<512, 256, 0, stream>>>(q, QrH, QrL, QiH, QiL, 64, 0, 1024, 1, sc * L2E);
  fft2_prep<1><<<2048, 256, 0, stream>>>(kv, KrH, KrL, KiH, KiL, 128, 0, 4096, 4, sc);
  fft2_prep<2><<<2048, 256, 0, stream>>>(kv, Vre, Vim, nullptr, nullptr, 128, 64, 4096, 4, 1.0f / 1024.0f);

  attn_mfma<<<256, 512, 0, stream>>>(KrH, KrL, KiH, KiL, QrH, QrL, QiH, QiL, Vre, Vim, out);
}